// Round 5
// baseline (1299.874 us; speedup 1.0000x reference)
//
#include <hip/hip_runtime.h>
#include <hip/hip_bf16.h>
#include <hip/hip_fp16.h>

// Problem constants: N=12288, E=393216, D=256, K=16
#define D 256
#define KCL 16
#define EPS 1e-15f
#define PAD 128            // ELL capacity; max degree (Poisson lambda=32) << 128
#define NBLK 1024          // persistent grid: 4 blocks/CU x 256 CUs
#define NTHR 256

typedef __attribute__((ext_vector_type(8))) short short8;
typedef __attribute__((ext_vector_type(4))) float f32x4;

__device__ __forceinline__ short bfhi(float v) {
    __hip_bfloat16 b = __float2bfloat16(v);
    return __builtin_bit_cast(short, b);
}
__device__ __forceinline__ float bf2f(short s) {
    __hip_bfloat16 b = __builtin_bit_cast(__hip_bfloat16, s);
    return __bfloat162float(b);
}

// grid-wide barrier: monotone counter, agent scope (cross-XCD safe).
// Each block: drain stores (__syncthreads waits own vmcnt) -> fence (L2 wb)
// -> arrive -> spin acquire (L2 inv on observe) -> __syncthreads.
__device__ __forceinline__ void gbar(int* cnt, int phase) {
    __syncthreads();
    if (threadIdx.x == 0) {
        __threadfence();
        __hip_atomic_fetch_add(cnt, 1, __ATOMIC_ACQ_REL, __HIP_MEMORY_SCOPE_AGENT);
        const int target = phase * NBLK;
        while (__hip_atomic_load(cnt, __ATOMIC_ACQUIRE, __HIP_MEMORY_SCOPE_AGENT) < target)
            __builtin_amdgcn_s_sleep(8);
        __threadfence();
    }
    __syncthreads();
}

// ---- split-bf16 MFMA GEMM phase: C[M,256] = fp16(A[M,256] @ B) ----
// B pre-transposed/split (Bth/Btl [col][k] bf16), fragments read from global (L2-hot).
__device__ void gemm_phase(const float* __restrict__ A,
                           const short* __restrict__ Bth,
                           const short* __restrict__ Btl,
                           __half* __restrict__ C,
                           char* smem, int N) {
    short (*Ah)[40] = (short(*)[40])smem;
    short (*Al)[40] = (short(*)[40])(smem + 5120);
    int tid = threadIdx.x;
    int lane = tid & 63, w = tid >> 6;
    int r  = tid >> 2;              // A-stage row 0..63
    int cc = (tid & 3) * 8;         // A-stage k-chunk
    int ar = w * 16 + (lane & 15);  // A-frag row
    int kq = (lane >> 4) * 8;       // frag k-chunk
    int njob = (N >> 6) * 4;        // 768

    for (int job = blockIdx.x; job < njob; job += NBLK) {
        int bm = (job >> 2) << 6, bn = (job & 3) << 6;
        f32x4 acc[4];
#pragma unroll
        for (int i = 0; i < 4; ++i) acc[i] = (f32x4){0.f, 0.f, 0.f, 0.f};

        for (int kk = 0; kk < D; kk += 32) {
            const float* ap = &A[(size_t)(bm + r) * D + kk + cc];
            float4 v0 = *(const float4*)ap;
            float4 v1 = *(const float4*)(ap + 4);
            float vv[8] = {v0.x, v0.y, v0.z, v0.w, v1.x, v1.y, v1.z, v1.w};
            short8 hi, lo;
#pragma unroll
            for (int j = 0; j < 8; ++j) {
                short h = bfhi(vv[j]);
                hi[j] = h;
                lo[j] = bfhi(vv[j] - bf2f(h));
            }
            __syncthreads();                 // WAR on prev k-step / prev phase
            *(short8*)&Ah[r][cc] = hi;
            *(short8*)&Al[r][cc] = lo;
            __syncthreads();

            short8 a_h = *(const short8*)&Ah[ar][kq];
            short8 a_l = *(const short8*)&Al[ar][kq];
#pragma unroll
            for (int nf = 0; nf < 4; ++nf) {
                int col = bn + nf * 16 + (lane & 15);
                short8 b_h = *(const short8*)&Bth[(size_t)col * D + kk + kq];
                short8 b_l = *(const short8*)&Btl[(size_t)col * D + kk + kq];
                acc[nf] = __builtin_amdgcn_mfma_f32_16x16x32_bf16(a_h, b_h, acc[nf], 0, 0, 0);
                acc[nf] = __builtin_amdgcn_mfma_f32_16x16x32_bf16(a_h, b_l, acc[nf], 0, 0, 0);
                acc[nf] = __builtin_amdgcn_mfma_f32_16x16x32_bf16(a_l, b_h, acc[nf], 0, 0, 0);
            }
        }
        // C/D layout: col=lane&15, row=(lane>>4)*4+rr  [m89-verified]
        int rbase = bm + w * 16 + (lane >> 4) * 4;
        int cb = bn + (lane & 15);
#pragma unroll
        for (int nf = 0; nf < 4; ++nf)
#pragma unroll
            for (int rr = 0; rr < 4; ++rr)
                C[(size_t)(rbase + rr) * D + cb + nf * 16] = __float2half(acc[nf][rr]);
    }
}

// ---- SpMM phase (ELL by dst), fp16 gather + bias + ReLU ----
__device__ void spmm_phase(const __half* __restrict__ h,
                           const int2* __restrict__ edges,
                           const int* __restrict__ deg,
                           const float* __restrict__ bias,
                           float* __restrict__ out,
                           char* smem, int N) {
    int2* se = (int2*)smem;
    int t = threadIdx.x;
    float bv = bias[t];
    for (int node = blockIdx.x; node < N; node += NBLK) {
        int n = min(deg[node], PAD);
        if (t < n) se[t] = edges[(size_t)node * PAD + t];
        __syncthreads();
        float acc = 0.f;
        int i = 0;
        for (; i + 4 <= n; i += 4) {
            int2 e0 = se[i], e1 = se[i + 1], e2 = se[i + 2], e3 = se[i + 3];
            float a0 = __half2float(h[(size_t)e0.x * D + t]);
            float a1 = __half2float(h[(size_t)e1.x * D + t]);
            float a2 = __half2float(h[(size_t)e2.x * D + t]);
            float a3 = __half2float(h[(size_t)e3.x * D + t]);
            acc = fmaf(__int_as_float(e0.y), a0, acc);
            acc = fmaf(__int_as_float(e1.y), a1, acc);
            acc = fmaf(__int_as_float(e2.y), a2, acc);
            acc = fmaf(__int_as_float(e3.y), a3, acc);
        }
        for (; i < n; ++i) {
            int2 e = se[i];
            acc = fmaf(__int_as_float(e.y), __half2float(h[(size_t)e.x * D + t]), acc);
        }
        out[(size_t)node * D + t] = fmaxf(acc + bv, 0.f);
        __syncthreads();                     // WAR before next node restage
    }
}

// ---- the mega kernel: all phases, grid-wide barriers between ----
__global__ __launch_bounds__(NTHR, 4) void mega_k(
        const float* __restrict__ x, const float* __restrict__ ew,
        const float* __restrict__ W1, const float* __restrict__ b1,
        const float* __restrict__ W2, const float* __restrict__ b2,
        const float* __restrict__ Wm, const float* __restrict__ bmv,
        const int* __restrict__ src, const int* __restrict__ dst,
        __half* __restrict__ G, float* __restrict__ H,
        int* __restrict__ deg, int* __restrict__ cnt, int* __restrict__ done,
        int2* __restrict__ edges,
        short* __restrict__ Wt1h, short* __restrict__ Wt1l,
        short* __restrict__ Wt2h, short* __restrict__ Wt2l,
        float* __restrict__ partial,
        float* __restrict__ s_out, float* __restrict__ loss_out,
        int N, int E) {
    __shared__ __align__(16) char smem[10368];
    __shared__ int lastFlag;
    int bid = blockIdx.x;
    int tid = threadIdx.x;

    // -------- phase S: weight prep (512 jobs) + ELL scatter (E/256 jobs) -----
    int nscat = (E + NTHR - 1) / NTHR;
    for (int job = bid; job < 512 + nscat; job += NBLK) {
        if (job < 512) {
            const float* W = (job < 256) ? W1 : W2;
            short* Th = (job < 256) ? Wt1h : Wt2h;
            short* Tl = (job < 256) ? Wt1l : Wt2l;
            int c = job & 255;
            float v = W[(size_t)tid * D + c];
            short h = bfhi(v);
            Th[(size_t)c * D + tid] = h;
            Tl[(size_t)c * D + tid] = bfhi(v - bf2f(h));
        } else {
            int e = (job - 512) * NTHR + tid;
            if (e < E) {
                int d = dst[e];
                int slot = atomicAdd(&deg[d], 1);
                if (slot < PAD)
                    edges[(size_t)d * PAD + slot] = make_int2(src[e], __float_as_int(ew[e]));
            }
        }
    }
    gbar(cnt, 1);
    gemm_phase(x, Wt1h, Wt1l, G, smem, N);
    gbar(cnt, 2);
    spmm_phase(G, edges, deg, b1, H, smem, N);
    gbar(cnt, 3);
    gemm_phase(H, Wt2h, Wt2l, G, smem, N);
    gbar(cnt, 4);
    spmm_phase(G, edges, deg, b2, H, smem, N);
    gbar(cnt, 5);

    // -------- phase C: cluster MLP + softmax + per-block sum s^2 -------------
    int wave = tid >> 6, lane = tid & 63;
    float sq[KCL];
#pragma unroll
    for (int j = 0; j < KCL; ++j) sq[j] = 0.f;

    for (int job = bid; job < (N >> 2); job += NBLK) {
        int node = job * 4 + wave;
        float4 hv = *(const float4*)&H[(size_t)node * D + lane * 4];
        float p[KCL];
#pragma unroll
        for (int j = 0; j < KCL; ++j) p[j] = 0.f;
        const float* hp = (const float*)&hv;
#pragma unroll
        for (int u = 0; u < 4; ++u) {
            float hval = hp[u];
            const float4* wrow = (const float4*)&Wm[(size_t)(lane * 4 + u) * KCL];
#pragma unroll
            for (int q = 0; q < 4; ++q) {
                float4 wv = wrow[q];
                p[q * 4 + 0] = fmaf(hval, wv.x, p[q * 4 + 0]);
                p[q * 4 + 1] = fmaf(hval, wv.y, p[q * 4 + 1]);
                p[q * 4 + 2] = fmaf(hval, wv.z, p[q * 4 + 2]);
                p[q * 4 + 3] = fmaf(hval, wv.w, p[q * 4 + 3]);
            }
        }
#pragma unroll
        for (int off = 32; off; off >>= 1)
#pragma unroll
            for (int j = 0; j < KCL; ++j) p[j] += __shfl_xor(p[j], off, 64);
        if (lane == 0) {
            float mx = -1e30f;
#pragma unroll
            for (int j = 0; j < KCL; ++j) { p[j] += bmv[j]; mx = fmaxf(mx, p[j]); }
            float sum = 0.f;
#pragma unroll
            for (int j = 0; j < KCL; ++j) { p[j] = __expf(p[j] - mx); sum += p[j]; }
            float inv = 1.f / sum;
#pragma unroll
            for (int j = 0; j < KCL; ++j) {
                p[j] *= inv;
                sq[j] = fmaf(p[j], p[j], sq[j]);
            }
            float* so = &s_out[(size_t)node * KCL];
#pragma unroll
            for (int q = 0; q < 4; ++q)
                *(float4*)&so[q * 4] = make_float4(p[q*4+0], p[q*4+1], p[q*4+2], p[q*4+3]);
        }
    }
    // block-level reduce of sq (lane0 of each wave holds partials)
    float (*dssq)[KCL] = (float(*)[KCL])smem;
    __syncthreads();
    if (lane == 0) {
#pragma unroll
        for (int j = 0; j < KCL; ++j) dssq[wave][j] = sq[j];
    }
    __syncthreads();
    if (tid < KCL)
        partial[(size_t)bid * KCL + tid] =
            dssq[0][tid] + dssq[1][tid] + dssq[2][tid] + dssq[3][tid];
    __syncthreads();   // drain partial store block-wide

    // -------- finale: last arriving block computes the loss ------------------
    if (tid == 0) {
        __threadfence();
        int old = __hip_atomic_fetch_add(done, 1, __ATOMIC_ACQ_REL, __HIP_MEMORY_SCOPE_AGENT);
        lastFlag = (old == NBLK - 1) ? 1 : 0;
    }
    __syncthreads();
    if (lastFlag) {
        int j = tid & 15, g = tid >> 4;
        float acc = 0.f;
        for (int rr = g; rr < NBLK; rr += 16)
            acc += __hip_atomic_load(&partial[(size_t)rr * KCL + j],
                                     __ATOMIC_RELAXED, __HIP_MEMORY_SCOPE_AGENT);
        float (*red)[17] = (float(*)[17])smem;
        __syncthreads();
        red[g][j] = acc;
        __syncthreads();
        if (tid == 0) {
            float sum = 0.f;
            for (int jj = 0; jj < KCL; ++jj) {
                float v = 0.f;
#pragma unroll
                for (int gg = 0; gg < 16; ++gg) v += red[gg][jj];
                sum += sqrtf(v + EPS);
            }
            loss_out[0] = -sum / sqrtf((float)N * (float)KCL);
        }
    }
}

extern "C" void kernel_launch(void* const* d_in, const int* in_sizes, int n_in,
                              void* d_out, int out_size, void* d_ws, size_t ws_size,
                              hipStream_t stream) {
    const float* x  = (const float*)d_in[0];
    const float* ew = (const float*)d_in[1];
    const float* W1 = (const float*)d_in[2];
    const float* b1 = (const float*)d_in[3];
    const float* W2 = (const float*)d_in[4];
    const float* b2 = (const float*)d_in[5];
    const float* Wm = (const float*)d_in[6];
    const float* bm = (const float*)d_in[7];
    const int*   ei = (const int*)d_in[8];

    const int N = in_sizes[0] / D;       // 12288
    const int E = in_sizes[1];           // 393216
    const int* src = ei;
    const int* dst = ei + E;

    float* out = (float*)d_out;

    // ws layout (deg | cnt | done contiguous -> one memset)
    char* ws = (char*)d_ws;
    __half* G    = (__half*)ws;       ws += (size_t)N * D * 2;      // gemm out (fp16)
    float* H     = (float*)ws;        ws += (size_t)N * D * 4;      // conv out
    int*   deg   = (int*)ws;          ws += (size_t)N * 4;
    int*   cnt   = (int*)ws;                                        // barrier counter
    int*   done  = (int*)(ws + 4);                                  // finale counter
    ws += 64;
    int2*  edges = (int2*)ws;         ws += (size_t)N * PAD * 8;
    short* Wt1h  = (short*)ws;        ws += (size_t)D * D * 2;
    short* Wt1l  = (short*)ws;        ws += (size_t)D * D * 2;
    short* Wt2h  = (short*)ws;        ws += (size_t)D * D * 2;
    short* Wt2l  = (short*)ws;        ws += (size_t)D * D * 2;
    float* partial = (float*)ws;      ws += (size_t)NBLK * KCL * 4;

    // zero deg + cnt + done in one memset
    hipMemsetAsync(deg, 0, (size_t)N * 4 + 64, stream);

    mega_k<<<NBLK, NTHR, 0, stream>>>(x, ew, W1, b1, W2, b2, Wm, bm,
                                      src, dst, G, H, deg, cnt, done, edges,
                                      Wt1h, Wt1l, Wt2h, Wt2l, partial,
                                      out, out + (size_t)N * KCL, N, E);
}

// Round 10
// 393.780 us; speedup vs baseline: 3.3010x; 3.3010x over previous
//
#include <hip/hip_runtime.h>
#include <hip/hip_bf16.h>
#include <hip/hip_fp16.h>

// Problem constants: N=12288, E=393216, D=256, K=16
#define D 256
#define KCL 16
#define EPS 1e-15f
#define PAD 128            // ELL capacity; max degree (Poisson lambda=32) << 128

typedef __attribute__((ext_vector_type(8))) short short8;
typedef __attribute__((ext_vector_type(4))) float f32x4;

__device__ __forceinline__ short bfhi(float v) {
    __hip_bfloat16 b = __float2bfloat16(v);
    return __builtin_bit_cast(short, b);
}
__device__ __forceinline__ float bf2f(short s) {
    __hip_bfloat16 b = __builtin_bit_cast(__hip_bfloat16, s);
    return __bfloat162float(b);
}

// ---------------- setup: weight prep (blocks 0..511) + ELL scatter (rest) ------
__global__ __launch_bounds__(256) void setup_k(const float* __restrict__ W1,
                                               const float* __restrict__ W2,
                                               short* __restrict__ Wt1h, short* __restrict__ Wt1l,
                                               short* __restrict__ Wt2h, short* __restrict__ Wt2l,
                                               const int* __restrict__ src,
                                               const int* __restrict__ dst,
                                               const float* __restrict__ ew,
                                               int* __restrict__ deg,
                                               int2* __restrict__ edges, int E) {
    int b = blockIdx.x;
    if (b < 512) {
        // W[k][c] -> Wt hi/lo bf16 [c][k]; writes coalesced along k
        const float* W = (b < 256) ? W1 : W2;
        short* Th = (b < 256) ? Wt1h : Wt2h;
        short* Tl = (b < 256) ? Wt1l : Wt2l;
        int c = b & 255;
        int k = threadIdx.x;
        float v = W[(size_t)k * D + c];
        short h = bfhi(v);
        Th[(size_t)c * D + k] = h;
        Tl[(size_t)c * D + k] = bfhi(v - bf2f(h));
    } else {
        int e = (b - 512) * 256 + threadIdx.x;
        if (e < E) {
            int d = dst[e];
            int slot = atomicAdd(&deg[d], 1);
            if (slot < PAD)
                edges[(size_t)d * PAD + slot] = make_int2(src[e], __float_as_int(ew[e]));
        }
    }
}

// ---------------- split-bf16 MFMA GEMM: C[M,256] = A[M,256] @ B, fp16 out --------
// B pre-transposed/split as Bth/Btl [col][k] bf16; fragments read from global (L2-hot).
#define GBM 64
#define APAD 40
__global__ __launch_bounds__(256) void gemm_k(const float* __restrict__ A,
                                              const short* __restrict__ Bth,
                                              const short* __restrict__ Btl,
                                              __half* __restrict__ C) {
    __shared__ short Ah[GBM][APAD];
    __shared__ short Al[GBM][APAD];
    int tid = threadIdx.x;
    int lane = tid & 63, w = tid >> 6;
    int bm = blockIdx.x * GBM, bn = blockIdx.y * 64;
    f32x4 acc[4];
#pragma unroll
    for (int i = 0; i < 4; ++i) acc[i] = (f32x4){0.f, 0.f, 0.f, 0.f};

    int r  = tid >> 2;             // A-stage row 0..63
    int cc = (tid & 3) * 8;        // A-stage k-chunk
    int ar = w * 16 + (lane & 15); // A-frag row
    int kq = (lane >> 4) * 8;      // frag k-chunk

    for (int kk = 0; kk < D; kk += 32) {
        const float* ap = &A[(size_t)(bm + r) * D + kk + cc];
        float4 v0 = *(const float4*)ap;
        float4 v1 = *(const float4*)(ap + 4);
        float vv[8] = {v0.x, v0.y, v0.z, v0.w, v1.x, v1.y, v1.z, v1.w};
        short8 hi, lo;
#pragma unroll
        for (int j = 0; j < 8; ++j) {
            short h = bfhi(vv[j]);
            hi[j] = h;
            lo[j] = bfhi(vv[j] - bf2f(h));
        }
        __syncthreads();                       // WAR: prev-iter reads done
        *(short8*)&Ah[r][cc] = hi;
        *(short8*)&Al[r][cc] = lo;
        __syncthreads();

        short8 a_h = *(const short8*)&Ah[ar][kq];
        short8 a_l = *(const short8*)&Al[ar][kq];
#pragma unroll
        for (int nf = 0; nf < 4; ++nf) {
            int col = bn + nf * 16 + (lane & 15);
            short8 b_h = *(const short8*)&Bth[(size_t)col * D + kk + kq];
            short8 b_l = *(const short8*)&Btl[(size_t)col * D + kk + kq];
            acc[nf] = __builtin_amdgcn_mfma_f32_16x16x32_bf16(a_h, b_h, acc[nf], 0, 0, 0);
            acc[nf] = __builtin_amdgcn_mfma_f32_16x16x32_bf16(a_h, b_l, acc[nf], 0, 0, 0);
            acc[nf] = __builtin_amdgcn_mfma_f32_16x16x32_bf16(a_l, b_h, acc[nf], 0, 0, 0);
        }
    }
    // epilogue: C/D layout col=lane&15, row=(lane>>4)*4+rr  [m89-verified]
    int rbase = bm + w * 16 + (lane >> 4) * 4;
    int cb = bn + (lane & 15);
#pragma unroll
    for (int nf = 0; nf < 4; ++nf)
#pragma unroll
        for (int rr = 0; rr < 4; ++rr)
            C[(size_t)(rbase + rr) * D + cb + nf * 16] = __float2half(acc[nf][rr]);
}

// ---------------- SpMM (ELL by dst), half2 gather + bias + ReLU -----------------
// 128 threads/block; thread t owns features 2t, 2t+1 (one dword gather per nbr).
__global__ __launch_bounds__(128) void spmm_k(const __half* __restrict__ h,
                                              const int2* __restrict__ edges,
                                              const int* __restrict__ deg,
                                              const float* __restrict__ bias,
                                              float* __restrict__ out) {
    int node = blockIdx.x;
    int t = threadIdx.x;                 // 0..127
    int n = min(deg[node], PAD);
    __shared__ int2 se[PAD];
    if (t < n) se[t] = edges[(size_t)node * PAD + t];
    __syncthreads();
    const __half2* h2 = (const __half2*)h;   // row stride D/2
    float acc0 = 0.f, acc1 = 0.f;
    int i = 0;
    for (; i + 4 <= n; i += 4) {
        int2 e0 = se[i], e1 = se[i + 1], e2 = se[i + 2], e3 = se[i + 3];
        float2 a0 = __half22float2(h2[(size_t)e0.x * (D / 2) + t]);
        float2 a1 = __half22float2(h2[(size_t)e1.x * (D / 2) + t]);
        float2 a2 = __half22float2(h2[(size_t)e2.x * (D / 2) + t]);
        float2 a3 = __half22float2(h2[(size_t)e3.x * (D / 2) + t]);
        float w0 = __int_as_float(e0.y), w1 = __int_as_float(e1.y);
        float w2 = __int_as_float(e2.y), w3 = __int_as_float(e3.y);
        acc0 = fmaf(w0, a0.x, acc0); acc1 = fmaf(w0, a0.y, acc1);
        acc0 = fmaf(w1, a1.x, acc0); acc1 = fmaf(w1, a1.y, acc1);
        acc0 = fmaf(w2, a2.x, acc0); acc1 = fmaf(w2, a2.y, acc1);
        acc0 = fmaf(w3, a3.x, acc0); acc1 = fmaf(w3, a3.y, acc1);
    }
    for (; i < n; ++i) {
        int2 e = se[i];
        float2 a = __half22float2(h2[(size_t)e.x * (D / 2) + t]);
        float wv = __int_as_float(e.y);
        acc0 = fmaf(wv, a.x, acc0); acc1 = fmaf(wv, a.y, acc1);
    }
    float2 bv = *(const float2*)&bias[2 * t];
    *(float2*)&out[(size_t)node * D + 2 * t] =
        make_float2(fmaxf(acc0 + bv.x, 0.f), fmaxf(acc1 + bv.y, 0.f));
}

// ------- cluster MLP + softmax + fused diag(s^T s) + loss (done-counter) --------
__global__ __launch_bounds__(256) void cluster_k(const float* __restrict__ h,
                                                 const float* __restrict__ Wm,
                                                 const float* __restrict__ bmv,
                                                 float* __restrict__ s_out,
                                                 float* __restrict__ partial,
                                                 int* __restrict__ done,
                                                 float* __restrict__ loss_out,
                                                 int N) {
    __shared__ float dssq[4][KCL];
    __shared__ int lastFlag;
    int tid = threadIdx.x;
    int wave = tid >> 6, lane = tid & 63;
    int node = blockIdx.x * 4 + wave;
    int nblk = N >> 2;   // gridDim.x

    float4 hv = *(const float4*)&h[(size_t)node * D + lane * 4];
    float p[KCL];
#pragma unroll
    for (int j = 0; j < KCL; ++j) p[j] = 0.f;
    const float* hp = (const float*)&hv;
#pragma unroll
    for (int u = 0; u < 4; ++u) {
        float hval = hp[u];
        const float4* wrow = (const float4*)&Wm[(size_t)(lane * 4 + u) * KCL];
#pragma unroll
        for (int q = 0; q < 4; ++q) {
            float4 wv = wrow[q];
            p[q * 4 + 0] = fmaf(hval, wv.x, p[q * 4 + 0]);
            p[q * 4 + 1] = fmaf(hval, wv.y, p[q * 4 + 1]);
            p[q * 4 + 2] = fmaf(hval, wv.z, p[q * 4 + 2]);
            p[q * 4 + 3] = fmaf(hval, wv.w, p[q * 4 + 3]);
        }
    }
#pragma unroll
    for (int off = 32; off; off >>= 1)
#pragma unroll
        for (int j = 0; j < KCL; ++j) p[j] += __shfl_xor(p[j], off, 64);
    if (lane == 0) {
        float mx = -1e30f;
#pragma unroll
        for (int j = 0; j < KCL; ++j) { p[j] += bmv[j]; mx = fmaxf(mx, p[j]); }
        float sum = 0.f;
#pragma unroll
        for (int j = 0; j < KCL; ++j) { p[j] = __expf(p[j] - mx); sum += p[j]; }
        float inv = 1.f / sum;
        float* so = &s_out[(size_t)node * KCL];
#pragma unroll
        for (int q = 0; q < 4; ++q) {
            float s0 = p[q*4+0] * inv, s1 = p[q*4+1] * inv;
            float s2 = p[q*4+2] * inv, s3 = p[q*4+3] * inv;
            *(float4*)&so[q * 4] = make_float4(s0, s1, s2, s3);
            dssq[wave][q*4+0] = s0 * s0; dssq[wave][q*4+1] = s1 * s1;
            dssq[wave][q*4+2] = s2 * s2; dssq[wave][q*4+3] = s3 * s3;
        }
    }
    __syncthreads();
    if (tid < KCL)
        partial[(size_t)blockIdx.x * KCL + tid] =
            dssq[0][tid] + dssq[1][tid] + dssq[2][tid] + dssq[3][tid];
    __syncthreads();

    // finale: last arriving block reduces all partials and writes the loss
    if (tid == 0) {
        __threadfence();
        int old = __hip_atomic_fetch_add(done, 1, __ATOMIC_ACQ_REL, __HIP_MEMORY_SCOPE_AGENT);
        lastFlag = (old == nblk - 1) ? 1 : 0;
    }
    __syncthreads();
    if (lastFlag) {
        __threadfence();
        int j = tid & 15, g = tid >> 4;
        float acc = 0.f;
        for (int rr = g; rr < nblk; rr += 16)
            acc += __hip_atomic_load(&partial[(size_t)rr * KCL + j],
                                     __ATOMIC_RELAXED, __HIP_MEMORY_SCOPE_AGENT);
        __shared__ float red2[16][17];
        red2[g][j] = acc;
        __syncthreads();
        if (tid == 0) {
            float sum = 0.f;
            for (int jj = 0; jj < KCL; ++jj) {
                float v = 0.f;
#pragma unroll
                for (int gg = 0; gg < 16; ++gg) v += red2[gg][jj];
                sum += sqrtf(v + EPS);
            }
            loss_out[0] = -sum / sqrtf((float)N * (float)KCL);
        }
    }
}

extern "C" void kernel_launch(void* const* d_in, const int* in_sizes, int n_in,
                              void* d_out, int out_size, void* d_ws, size_t ws_size,
                              hipStream_t stream) {
    const float* x  = (const float*)d_in[0];
    const float* ew = (const float*)d_in[1];
    const float* W1 = (const float*)d_in[2];
    const float* b1 = (const float*)d_in[3];
    const float* W2 = (const float*)d_in[4];
    const float* b2 = (const float*)d_in[5];
    const float* Wm = (const float*)d_in[6];
    const float* bm = (const float*)d_in[7];
    const int*   ei = (const int*)d_in[8];

    const int N = in_sizes[0] / D;       // 12288
    const int E = in_sizes[1];           // 393216
    const int* src = ei;
    const int* dst = ei + E;

    float* out = (float*)d_out;

    // ws layout (deg | done contiguous -> one memset)
    char* ws = (char*)d_ws;
    __half* G    = (__half*)ws;       ws += (size_t)N * D * 2;      // gemm out (fp16)
    float* H     = (float*)ws;        ws += (size_t)N * D * 4;      // conv out
    int*   deg   = (int*)ws;          ws += (size_t)N * 4;
    int*   done  = (int*)ws;          ws += 64;
    int2*  edges = (int2*)ws;         ws += (size_t)N * PAD * 8;
    short* Wt1h  = (short*)ws;        ws += (size_t)D * D * 2;
    short* Wt1l  = (short*)ws;        ws += (size_t)D * D * 2;
    short* Wt2h  = (short*)ws;        ws += (size_t)D * D * 2;
    short* Wt2l  = (short*)ws;        ws += (size_t)D * D * 2;
    float* partial = (float*)ws;      ws += (size_t)(N / 4) * KCL * 4;

    // zero deg + done in one memset
    hipMemsetAsync(deg, 0, (size_t)N * 4 + 64, stream);
    // fused weight prep + ELL scatter
    int gE = (E + 255) / 256;
    setup_k<<<512 + gE, 256, 0, stream>>>(W1, W2, Wt1h, Wt1l, Wt2h, Wt2l,
                                          src, dst, ew, deg, edges, E);

    dim3 ggrid(N / GBM, 4);
    // conv1: G = fp16(x @ W1) ; H = relu(scatter(G) + b1)
    gemm_k<<<ggrid, 256, 0, stream>>>(x, Wt1h, Wt1l, G);
    spmm_k<<<N, 128, 0, stream>>>(G, edges, deg, b1, H);
    // conv2
    gemm_k<<<ggrid, 256, 0, stream>>>(H, Wt2h, Wt2l, G);
    spmm_k<<<N, 128, 0, stream>>>(G, edges, deg, b2, H);
    // cluster assignment -> s (d_out) + fused loss
    cluster_k<<<N / 4, 256, 0, stream>>>(H, Wm, bm, out, partial, done,
                                         out + (size_t)N * KCL, N);
}

// Round 11
// 240.414 us; speedup vs baseline: 5.4068x; 1.6379x over previous
//
#include <hip/hip_runtime.h>
#include <hip/hip_bf16.h>
#include <hip/hip_fp16.h>

// Problem constants: N=12288, E=393216, D=256, K=16
#define D 256
#define KCL 16
#define EPS 1e-15f
#define PAD 128            // ELL capacity; max degree (Poisson lambda=32) << 128

typedef __attribute__((ext_vector_type(8))) short short8;
typedef __attribute__((ext_vector_type(4))) float f32x4;

__device__ __forceinline__ short bfhi(float v) {
    __hip_bfloat16 b = __float2bfloat16(v);
    return __builtin_bit_cast(short, b);
}
__device__ __forceinline__ float bf2f(short s) {
    __hip_bfloat16 b = __builtin_bit_cast(__hip_bfloat16, s);
    return __bfloat162float(b);
}

// ---------------- setup: weight prep (blocks 0..511) + ELL scatter (rest) ------
__global__ __launch_bounds__(256) void setup_k(const float* __restrict__ W1,
                                               const float* __restrict__ W2,
                                               short* __restrict__ Wt1h, short* __restrict__ Wt1l,
                                               short* __restrict__ Wt2h, short* __restrict__ Wt2l,
                                               const int* __restrict__ src,
                                               const int* __restrict__ dst,
                                               const float* __restrict__ ew,
                                               int* __restrict__ deg,
                                               int2* __restrict__ edges, int E) {
    int b = blockIdx.x;
    if (b < 512) {
        // W[k][c] -> Wt hi/lo bf16 [c][k]; writes coalesced along k
        const float* W = (b < 256) ? W1 : W2;
        short* Th = (b < 256) ? Wt1h : Wt2h;
        short* Tl = (b < 256) ? Wt1l : Wt2l;
        int c = b & 255;
        int k = threadIdx.x;
        float v = W[(size_t)k * D + c];
        short h = bfhi(v);
        Th[(size_t)c * D + k] = h;
        Tl[(size_t)c * D + k] = bfhi(v - bf2f(h));
    } else {
        int e = (b - 512) * 256 + threadIdx.x;
        if (e < E) {
            int d = dst[e];
            int slot = atomicAdd(&deg[d], 1);
            if (slot < PAD)
                edges[(size_t)d * PAD + slot] = make_int2(src[e], __float_as_int(ew[e]));
        }
    }
}

// ---------------- split-bf16 MFMA GEMM: C[M,256] = A[M,256] @ B, fp16 out --------
// B pre-transposed/split as Bth/Btl [col][k] bf16; fragments read from global (L2-hot).
#define GBM 64
#define APAD 40
__global__ __launch_bounds__(256) void gemm_k(const float* __restrict__ A,
                                              const short* __restrict__ Bth,
                                              const short* __restrict__ Btl,
                                              __half* __restrict__ C) {
    __shared__ short Ah[GBM][APAD];
    __shared__ short Al[GBM][APAD];
    int tid = threadIdx.x;
    int lane = tid & 63, w = tid >> 6;
    int bm = blockIdx.x * GBM, bn = blockIdx.y * 64;
    f32x4 acc[4];
#pragma unroll
    for (int i = 0; i < 4; ++i) acc[i] = (f32x4){0.f, 0.f, 0.f, 0.f};

    int r  = tid >> 2;             // A-stage row 0..63
    int cc = (tid & 3) * 8;        // A-stage k-chunk
    int ar = w * 16 + (lane & 15); // A-frag row
    int kq = (lane >> 4) * 8;      // frag k-chunk

    for (int kk = 0; kk < D; kk += 32) {
        const float* ap = &A[(size_t)(bm + r) * D + kk + cc];
        float4 v0 = *(const float4*)ap;
        float4 v1 = *(const float4*)(ap + 4);
        float vv[8] = {v0.x, v0.y, v0.z, v0.w, v1.x, v1.y, v1.z, v1.w};
        short8 hi, lo;
#pragma unroll
        for (int j = 0; j < 8; ++j) {
            short h = bfhi(vv[j]);
            hi[j] = h;
            lo[j] = bfhi(vv[j] - bf2f(h));
        }
        __syncthreads();                       // WAR: prev-iter reads done
        *(short8*)&Ah[r][cc] = hi;
        *(short8*)&Al[r][cc] = lo;
        __syncthreads();

        short8 a_h = *(const short8*)&Ah[ar][kq];
        short8 a_l = *(const short8*)&Al[ar][kq];
#pragma unroll
        for (int nf = 0; nf < 4; ++nf) {
            int col = bn + nf * 16 + (lane & 15);
            short8 b_h = *(const short8*)&Bth[(size_t)col * D + kk + kq];
            short8 b_l = *(const short8*)&Btl[(size_t)col * D + kk + kq];
            acc[nf] = __builtin_amdgcn_mfma_f32_16x16x32_bf16(a_h, b_h, acc[nf], 0, 0, 0);
            acc[nf] = __builtin_amdgcn_mfma_f32_16x16x32_bf16(a_h, b_l, acc[nf], 0, 0, 0);
            acc[nf] = __builtin_amdgcn_mfma_f32_16x16x32_bf16(a_l, b_h, acc[nf], 0, 0, 0);
        }
    }
    // epilogue: C/D layout col=lane&15, row=(lane>>4)*4+rr  [m89-verified]
    int rbase = bm + w * 16 + (lane >> 4) * 4;
    int cb = bn + (lane & 15);
#pragma unroll
    for (int nf = 0; nf < 4; ++nf)
#pragma unroll
        for (int rr = 0; rr < 4; ++rr)
            C[(size_t)(rbase + rr) * D + cb + nf * 16] = __float2half(acc[nf][rr]);
}

// ---------------- SpMM (ELL by dst), half2 gather + bias + ReLU -----------------
// 128 threads/block; thread t owns features 2t, 2t+1 (one dword gather per nbr).
__global__ __launch_bounds__(128) void spmm_k(const __half* __restrict__ h,
                                              const int2* __restrict__ edges,
                                              const int* __restrict__ deg,
                                              const float* __restrict__ bias,
                                              float* __restrict__ out) {
    int node = blockIdx.x;
    int t = threadIdx.x;                 // 0..127
    int n = min(deg[node], PAD);
    __shared__ int2 se[PAD];
    if (t < n) se[t] = edges[(size_t)node * PAD + t];
    __syncthreads();
    const __half2* h2 = (const __half2*)h;   // row stride D/2
    float acc0 = 0.f, acc1 = 0.f;
    int i = 0;
    for (; i + 4 <= n; i += 4) {
        int2 e0 = se[i], e1 = se[i + 1], e2 = se[i + 2], e3 = se[i + 3];
        float2 a0 = __half22float2(h2[(size_t)e0.x * (D / 2) + t]);
        float2 a1 = __half22float2(h2[(size_t)e1.x * (D / 2) + t]);
        float2 a2 = __half22float2(h2[(size_t)e2.x * (D / 2) + t]);
        float2 a3 = __half22float2(h2[(size_t)e3.x * (D / 2) + t]);
        float w0 = __int_as_float(e0.y), w1 = __int_as_float(e1.y);
        float w2 = __int_as_float(e2.y), w3 = __int_as_float(e3.y);
        acc0 = fmaf(w0, a0.x, acc0); acc1 = fmaf(w0, a0.y, acc1);
        acc0 = fmaf(w1, a1.x, acc0); acc1 = fmaf(w1, a1.y, acc1);
        acc0 = fmaf(w2, a2.x, acc0); acc1 = fmaf(w2, a2.y, acc1);
        acc0 = fmaf(w3, a3.x, acc0); acc1 = fmaf(w3, a3.y, acc1);
    }
    for (; i < n; ++i) {
        int2 e = se[i];
        float2 a = __half22float2(h2[(size_t)e.x * (D / 2) + t]);
        float wv = __int_as_float(e.y);
        acc0 = fmaf(wv, a.x, acc0); acc1 = fmaf(wv, a.y, acc1);
    }
    float2 bv = *(const float2*)&bias[2 * t];
    *(float2*)&out[(size_t)node * D + 2 * t] =
        make_float2(fmaxf(acc0 + bv.x, 0.f), fmaxf(acc1 + bv.y, 0.f));
}

// ------- cluster MLP + softmax; writes s + per-block s^2 partials ---------------
__global__ __launch_bounds__(256) void cluster_k(const float* __restrict__ h,
                                                 const float* __restrict__ Wm,
                                                 const float* __restrict__ bmv,
                                                 float* __restrict__ s_out,
                                                 float* __restrict__ partial) {
    __shared__ float dssq[4][KCL];
    int tid = threadIdx.x;
    int wave = tid >> 6, lane = tid & 63;
    int node = blockIdx.x * 4 + wave;

    float4 hv = *(const float4*)&h[(size_t)node * D + lane * 4];
    float p[KCL];
#pragma unroll
    for (int j = 0; j < KCL; ++j) p[j] = 0.f;
    const float* hp = (const float*)&hv;
#pragma unroll
    for (int u = 0; u < 4; ++u) {
        float hval = hp[u];
        const float4* wrow = (const float4*)&Wm[(size_t)(lane * 4 + u) * KCL];
#pragma unroll
        for (int q = 0; q < 4; ++q) {
            float4 wv = wrow[q];
            p[q * 4 + 0] = fmaf(hval, wv.x, p[q * 4 + 0]);
            p[q * 4 + 1] = fmaf(hval, wv.y, p[q * 4 + 1]);
            p[q * 4 + 2] = fmaf(hval, wv.z, p[q * 4 + 2]);
            p[q * 4 + 3] = fmaf(hval, wv.w, p[q * 4 + 3]);
        }
    }
#pragma unroll
    for (int off = 32; off; off >>= 1)
#pragma unroll
        for (int j = 0; j < KCL; ++j) p[j] += __shfl_xor(p[j], off, 64);
    if (lane == 0) {
        float mx = -1e30f;
#pragma unroll
        for (int j = 0; j < KCL; ++j) { p[j] += bmv[j]; mx = fmaxf(mx, p[j]); }
        float sum = 0.f;
#pragma unroll
        for (int j = 0; j < KCL; ++j) { p[j] = __expf(p[j] - mx); sum += p[j]; }
        float inv = 1.f / sum;
        float* so = &s_out[(size_t)node * KCL];
#pragma unroll
        for (int q = 0; q < 4; ++q) {
            float s0 = p[q*4+0] * inv, s1 = p[q*4+1] * inv;
            float s2 = p[q*4+2] * inv, s3 = p[q*4+3] * inv;
            *(float4*)&so[q * 4] = make_float4(s0, s1, s2, s3);
            dssq[wave][q*4+0] = s0 * s0; dssq[wave][q*4+1] = s1 * s1;
            dssq[wave][q*4+2] = s2 * s2; dssq[wave][q*4+3] = s3 * s3;
        }
    }
    __syncthreads();
    if (tid < KCL)
        partial[(size_t)blockIdx.x * KCL + tid] =
            dssq[0][tid] + dssq[1][tid] + dssq[2][tid] + dssq[3][tid];
}

// ------- final: reduce 3072x16 partials (plain coalesced loads) + loss ----------
__global__ __launch_bounds__(1024) void final_k(const float* __restrict__ partial,
                                                float* __restrict__ loss_out,
                                                int nblk, int N) {
    int tid = threadIdx.x;                   // 0..1023
    int total = nblk * KCL;                  // 49152
    float acc = 0.f;
    for (int idx = tid; idx < total; idx += 1024)   // coalesced, j = idx & 15 fixed
        acc += partial[idx];
    int j = tid & 15, g = tid >> 4;          // 64 groups
    __shared__ float red[64][KCL + 1];
    red[g][j] = acc;
    __syncthreads();
    if (tid < KCL) {
        float v = 0.f;
#pragma unroll
        for (int gg = 0; gg < 64; ++gg) v += red[gg][tid];
        red[0][tid] = sqrtf(v + EPS);
    }
    __syncthreads();
    if (tid == 0) {
        float sum = 0.f;
#pragma unroll
        for (int jj = 0; jj < KCL; ++jj) sum += red[0][jj];
        loss_out[0] = -sum / sqrtf((float)N * (float)KCL);
    }
}

extern "C" void kernel_launch(void* const* d_in, const int* in_sizes, int n_in,
                              void* d_out, int out_size, void* d_ws, size_t ws_size,
                              hipStream_t stream) {
    const float* x  = (const float*)d_in[0];
    const float* ew = (const float*)d_in[1];
    const float* W1 = (const float*)d_in[2];
    const float* b1 = (const float*)d_in[3];
    const float* W2 = (const float*)d_in[4];
    const float* b2 = (const float*)d_in[5];
    const float* Wm = (const float*)d_in[6];
    const float* bm = (const float*)d_in[7];
    const int*   ei = (const int*)d_in[8];

    const int N = in_sizes[0] / D;       // 12288
    const int E = in_sizes[1];           // 393216
    const int* src = ei;
    const int* dst = ei + E;

    float* out = (float*)d_out;

    // ws layout
    char* ws = (char*)d_ws;
    __half* G    = (__half*)ws;       ws += (size_t)N * D * 2;      // gemm out (fp16)
    float* H     = (float*)ws;        ws += (size_t)N * D * 4;      // conv out
    int*   deg   = (int*)ws;          ws += (size_t)N * 4;
    int2*  edges = (int2*)ws;         ws += (size_t)N * PAD * 8;
    short* Wt1h  = (short*)ws;        ws += (size_t)D * D * 2;
    short* Wt1l  = (short*)ws;        ws += (size_t)D * D * 2;
    short* Wt2h  = (short*)ws;        ws += (size_t)D * D * 2;
    short* Wt2l  = (short*)ws;        ws += (size_t)D * D * 2;
    float* partial = (float*)ws;      ws += (size_t)(N / 4) * KCL * 4;

    // zero deg
    hipMemsetAsync(deg, 0, (size_t)N * 4, stream);
    // fused weight prep + ELL scatter
    int gE = (E + 255) / 256;
    setup_k<<<512 + gE, 256, 0, stream>>>(W1, W2, Wt1h, Wt1l, Wt2h, Wt2l,
                                          src, dst, ew, deg, edges, E);

    dim3 ggrid(N / GBM, 4);
    // conv1: G = fp16(x @ W1) ; H = relu(scatter(G) + b1)
    gemm_k<<<ggrid, 256, 0, stream>>>(x, Wt1h, Wt1l, G);
    spmm_k<<<N, 128, 0, stream>>>(G, edges, deg, b1, H);
    // conv2
    gemm_k<<<ggrid, 256, 0, stream>>>(H, Wt2h, Wt2l, G);
    spmm_k<<<N, 128, 0, stream>>>(G, edges, deg, b2, H);
    // cluster assignment -> s (d_out) + per-block partials, then tiny final reduce
    cluster_k<<<N / 4, 256, 0, stream>>>(H, Wm, bm, out, partial);
    final_k<<<1, 1024, 0, stream>>>(partial, out + (size_t)N * KCL, N / 4, N);
}